// Round 8
// baseline (49964.548 us; speedup 1.0000x reference)
//
#include <hip/hip_runtime.h>
#include <hip/hip_bf16.h>

#define B_   256
#define L_   336
#define NIN  8
#define H_   512
#define PL_  96
#define KC   64
#define BT   32
#define GT   128

typedef unsigned short u16;
typedef __attribute__((ext_vector_type(8))) short short8;
typedef __attribute__((ext_vector_type(4))) float f32x4;

__device__ __forceinline__ float sigm(float x)   { return 1.0f / (1.0f + __expf(-x)); }
__device__ __forceinline__ float tanhf_(float x) { return 1.0f - 2.0f / (1.0f + __expf(2.0f * x)); }
__device__ __forceinline__ u16 f2b(float f) {
    __hip_bfloat16 h = __float2bfloat16(f);
    return __builtin_bit_cast(u16, h);
}
__device__ __forceinline__ float b2f(u16 u) {
    union { unsigned int i; float f; } v; v.i = ((unsigned int)u) << 16; return v.f;
}

struct Seg { const u16* src; int stride; const u16* W; int nch; int ldw; };

// Full-batch block: [256 batch rows x 128 gate rows]. Weights for this block's
// 128 gate rows are staged ONCE per K-chunk (no batch-tile redundancy — the
// baseline staged each weight row 8x). A-panel holds all 256 rows per chunk.
struct SM2 {
    u16   w_s[GT][KC + 8];      // 18.4 KB
    u16   in_s[B_][KC + 8];     // 36.9 KB
    float g_s[GT][BT + 1];      // 16.9 KB (one batch-tile at a time, epilogue)
};

// gates GEMM over two segments + LSTM cell, full batch per block.
// All fragment/index math identical to the verified baseline kernel.
__device__ void gates_gemm_cell_fb(const Seg* segs,
    const float* __restrict__ bias, const float* __restrict__ w0col,
    const float* __restrict__ yprev,
    float* __restrict__ cbuf, u16* __restrict__ hbf_out, float* __restrict__ hf_out,
    u16* __restrict__ Ebuf, int te, int j0, SM2& sm)
{
    const int tid = threadIdx.x;
    const int wv = tid >> 6, lane = tid & 63;
    f32x4 acc[8][2][2] = {};   // [batch-tile][m-tile][n-tile] — fully unrolled use

    for (int s = 0; s < 2; ++s) {
        const Seg sg = segs[s];
        for (int c = 0; c < sg.nch; ++c) {
            const int k0 = c * KC;
            __syncthreads();
            #pragma unroll
            for (int i = 0; i < 4; ++i) {  // stage W: 128 rows x 64 bf16 = 1024 uint4
                const int idx = tid + (i << 8);
                const int gi = idx >> 3, kq = idx & 7;
                const int row = ((gi >> 5) << 9) + j0 + (gi & 31);   // q*512 + j0 + u
                const uint4* p = (const uint4*)(sg.W + (size_t)row * sg.ldw + k0) + kq;
                *(uint4*)&sm.w_s[gi][kq << 3] = *p;
            }
            #pragma unroll
            for (int i = 0; i < 8; ++i) {  // stage A: 256 rows x 64 bf16 = 2048 uint4
                const int idx = tid + (i << 8);
                const int r = idx >> 3, kq = idx & 7;
                const uint4* p = (const uint4*)(sg.src + (size_t)r * sg.stride + k0) + kq;
                *(uint4*)&sm.in_s[r][kq << 3] = *p;
            }
            __syncthreads();
            #pragma unroll
            for (int ks = 0; ks < 2; ++ks) {
                const int kk = (ks << 5) + ((lane >> 4) << 3);
                #pragma unroll
                for (int bt = 0; bt < 8; ++bt) {
                    short8 a0 = *(const short8*)&sm.in_s[(bt << 5) + (lane & 15)][kk];
                    short8 a1 = *(const short8*)&sm.in_s[(bt << 5) + 16 + (lane & 15)][kk];
                    #pragma unroll
                    for (int nt = 0; nt < 2; ++nt) {
                        const int gi = (((wv << 1) + nt) << 4) + (lane & 15);
                        short8 bb = *(const short8*)&sm.w_s[gi][kk];
                        acc[bt][0][nt] = __builtin_amdgcn_mfma_f32_16x16x32_bf16(a0, bb, acc[bt][0][nt], 0, 0, 0);
                        acc[bt][1][nt] = __builtin_amdgcn_mfma_f32_16x16x32_bf16(a1, bb, acc[bt][1][nt], 0, 0, 0);
                    }
                }
            }
        }
    }

    // epilogue per batch-tile: g_s exchange + cell (verbatim baseline math)
    #pragma unroll
    for (int bt = 0; bt < 8; ++bt) {
        const int batch0 = bt << 5;
        __syncthreads();
        // C/D layout (m89-verified): col(n)=lane&15, row(m)=(lane>>4)*4+reg
        #pragma unroll
        for (int mt = 0; mt < 2; ++mt)
            #pragma unroll
            for (int nt = 0; nt < 2; ++nt) {
                const int gi = (((wv << 1) + nt) << 4) + (lane & 15);
                const int brow = (mt << 4) + ((lane >> 4) << 2);
                #pragma unroll
                for (int r = 0; r < 4; ++r)
                    sm.g_s[gi][brow + r] = acc[bt][mt][nt][r];
            }
        __syncthreads();

        #pragma unroll
        for (int e = 0; e < 4; ++e) {
            const int idx = tid + (e << 8);
            const int b = idx >> 5, j = idx & 31;
            const int bg = batch0 + b, jg = j0 + j;
            float pre[4];
            #pragma unroll
            for (int q = 0; q < 4; ++q) {
                const int r = (q << 9) + jg;
                float v = sm.g_s[(q << 5) + j][b] + bias[r];
                if (w0col) v += yprev[bg] * w0col[r];
                pre[q] = v;
            }
            const float iv = sigm(pre[0]);
            const float fv = sigm(pre[1]);
            const float gv = tanhf_(pre[2]);
            const float ov = sigm(pre[3]);
            const size_t ci = ((size_t)bg << 9) + jg;
            const float cold = cbuf[ci];
            const float cn = fv * cold + iv * gv;
            const float hn = ov * tanhf_(cn);
            cbuf[ci] = cn;
            hbf_out[ci] = f2b(hn);
            if (hf_out) hf_out[ci] = hn;
            if (Ebuf) Ebuf[((size_t)bg * L_ + te) * H_ + jg] = f2b(hn);
        }
    }
}

// Pipelined encoder: blocks 0..15 do L0 step tau; 16..31 do L1 step tau-1.
__global__ __launch_bounds__(256) void enc_step2_kernel(
    const u16* __restrict__ xpad, const u16* __restrict__ Wih0p, const u16* __restrict__ Whh0b,
    const float* __restrict__ bias0,
    const u16* __restrict__ Wih1b, const u16* __restrict__ Whh1b, const float* __restrict__ bias1,
    u16* h0a, u16* h0b, float* c0,
    u16* h1a, u16* h1b, float* h1fa, float* h1fb, float* c1,
    u16* E, int tau)
{
    __shared__ SM2 sm;
    const int bid = blockIdx.x;
    if (bid < 16) {
        if (tau >= L_) return;
        Seg segs[2];
        segs[0] = { xpad + tau * KC, L_ * KC, Wih0p, 1, KC };
        segs[1] = { (tau & 1) ? h0b : h0a, H_, Whh0b, 8, H_ };
        gates_gemm_cell_fb(segs, bias0, nullptr, nullptr, c0,
                           (tau & 1) ? h0a : h0b, nullptr, nullptr, 0,
                           bid * 32, sm);
    } else {
        if (tau == 0) return;
        const int te = tau - 1;
        Seg segs[2];
        segs[0] = { (tau & 1) ? h0b : h0a, H_, Wih1b, 8, H_ };  // ys0[te]
        segs[1] = { (te & 1) ? h1b : h1a, H_, Whh1b, 8, H_ };
        gates_gemm_cell_fb(segs, bias1, nullptr, nullptr, c1,
                           (te & 1) ? h1a : h1b, (te & 1) ? h1fa : h1fb, E, te,
                           (bid - 16) * 32, sm);
    }
}

__global__ __launch_bounds__(256) void dec_step2_kernel(
    const u16* __restrict__ ctxb, const float* __restrict__ yprev,
    const u16* __restrict__ Wdihb, const u16* __restrict__ Wdhhb,
    const float* __restrict__ biasd, const float* __restrict__ w0col,
    u16* h1a, u16* h1b, float* h1fa, float* h1fb, float* c1, int t)
{
    __shared__ SM2 sm;
    Seg segs[2];
    segs[0] = { ctxb, H_, Wdihb, 8, H_ };
    segs[1] = { (t & 1) ? h1b : h1a, H_, Wdhhb, 8, H_ };
    gates_gemm_cell_fb(segs, biasd, w0col, yprev, c1,
                       (t & 1) ? h1a : h1b, (t & 1) ? h1fa : h1fb, nullptr, 0,
                       blockIdx.x * 32, sm);
}

// One block per batch row. Computes y_{step-1} = h.Wfc + b, then flash-style
// online-softmax attention over E (single pass), writes ctx (bf16). Verified.
__global__ __launch_bounds__(256) void attn_step_kernel(
    const float* __restrict__ hf, const u16* __restrict__ E,
    const float* __restrict__ Wfc, const float* __restrict__ bfc,
    u16* __restrict__ ctxb, float* __restrict__ yprev,
    float* __restrict__ out, int step)
{
    __shared__ float hs[H_];
    __shared__ float red[256];
    __shared__ u16 Es[48 * H_];
    __shared__ float scores[48];
    const int tid = threadIdx.x;
    const int b = blockIdx.x;

    hs[tid]       = hf[((size_t)b << 9) + tid];
    hs[tid + 256] = hf[((size_t)b << 9) + tid + 256];
    __syncthreads();

    float p = hs[tid] * Wfc[tid] + hs[tid + 256] * Wfc[tid + 256];
    red[tid] = p;
    __syncthreads();
    for (int s = 128; s > 0; s >>= 1) {
        if (tid < s) red[tid] += red[tid + s];
        __syncthreads();
    }
    if (tid == 0) {
        if (step > 0) {
            float y = red[0] + bfc[0];
            yprev[b] = y;
            out[b * PL_ + (step - 1)] = y;
        } else {
            yprev[b] = 0.0f;   // reference: y0 = zeros
        }
    }
    if (step == PL_) return;   // final launch: y only

    const int wv = tid >> 6, lane = tid & 63;
    float m = -1e30f, d = 0.0f, c0a = 0.0f, c1a = 0.0f;
    const int k0 = tid, k1 = tid + 256;

    for (int l0 = 0; l0 < L_; l0 += 48) {
        __syncthreads();
        {
            const uint4* src = (const uint4*)(E + (((size_t)b * L_ + l0) << 9));
            uint4* dst = (uint4*)Es;
            #pragma unroll
            for (int i = 0; i < 12; ++i)
                dst[tid + (i << 8)] = src[tid + (i << 8)];
        }
        __syncthreads();
        #pragma unroll
        for (int s = 0; s < 12; ++s) {
            const int l = wv * 12 + s;
            const u16* er = &Es[(l << 9) + (lane << 3)];
            float acc = 0.f;
            #pragma unroll
            for (int j = 0; j < 8; ++j)
                acc += hs[(lane << 3) + j] * b2f(er[j]);
            #pragma unroll
            for (int off = 32; off > 0; off >>= 1)
                acc += __shfl_xor(acc, off);
            if (lane == 0) scores[l] = acc;
        }
        __syncthreads();
        float mc = m;
        #pragma unroll
        for (int l = 0; l < 48; ++l) mc = fmaxf(mc, scores[l]);
        const float alpha = __expf(m - mc);
        d *= alpha; c0a *= alpha; c1a *= alpha;
        for (int l = 0; l < 48; ++l) {
            const float pl = __expf(scores[l] - mc);
            d += pl;
            c0a += pl * b2f(Es[(l << 9) + k0]);
            c1a += pl * b2f(Es[(l << 9) + k1]);
        }
        m = mc;
    }
    const float inv = 1.0f / d;
    ctxb[((size_t)b << 9) + k0] = f2b(c0a * inv);
    ctxb[((size_t)b << 9) + k1] = f2b(c1a * inv);
}

// One-time (per call) weight conversion fp32->bf16, bias fusion, x padding to K=64.
__global__ __launch_bounds__(256) void prep_kernel(
    const float* __restrict__ x,
    const float* __restrict__ Wih0, const float* __restrict__ Whh0,
    const float* __restrict__ bih0, const float* __restrict__ bhh0,
    const float* __restrict__ Wih1, const float* __restrict__ Whh1,
    const float* __restrict__ bih1, const float* __restrict__ bhh1,
    const float* __restrict__ Wdih, const float* __restrict__ Wdhh,
    const float* __restrict__ bihd, const float* __restrict__ bhhd,
    u16* Wih0p, u16* Whh0b, u16* Wih1b, u16* Whh1b, u16* Wdihb, u16* Wdhhb,
    float* w0col, float* bias0, float* bias1, float* biasd, u16* xpad)
{
    const long E0 = 131072;
    const long E1 = E0 + 1048576;
    const long E2 = E1 + 1048576;
    const long E3 = E2 + 1048576;
    const long E4 = E3 + 1048576;
    const long E5 = E4 + 1048576;
    const long E6 = E5 + 2048;
    const long E7 = E6 + 2048;
    const long E8 = E7 + 2048;
    const long E9 = E8 + 2048;
    const long E10 = E9 + (long)B_ * L_ * KC;
    for (long idx = (long)blockIdx.x * 256 + threadIdx.x; idx < E10;
         idx += (long)gridDim.x * 256) {
        if (idx < E0) {
            long r = idx >> 6, cc = idx & 63;
            Wih0p[idx] = f2b(cc < NIN ? Wih0[(r << 3) + cc] : 0.0f);
        } else if (idx < E1) { long j = idx - E0; Whh0b[j] = f2b(Whh0[j]);
        } else if (idx < E2) { long j = idx - E1; Wih1b[j] = f2b(Wih1[j]);
        } else if (idx < E3) { long j = idx - E2; Whh1b[j] = f2b(Whh1[j]);
        } else if (idx < E4) {
            long j = idx - E3; long r = j >> 9, cc = j & 511;
            Wdihb[j] = f2b(Wdih[r * 513 + 1 + cc]);
        } else if (idx < E5) { long j = idx - E4; Wdhhb[j] = f2b(Wdhh[j]);
        } else if (idx < E6) { long j = idx - E5; w0col[j] = Wdih[j * 513];
        } else if (idx < E7) { long j = idx - E6; bias0[j] = bih0[j] + bhh0[j];
        } else if (idx < E8) { long j = idx - E7; bias1[j] = bih1[j] + bhh1[j];
        } else if (idx < E9) { long j = idx - E8; biasd[j] = bihd[j] + bhhd[j];
        } else {
            long j = idx - E9;
            long b = j / (L_ * KC);
            long rest = j - b * (L_ * KC);
            long l = rest >> 6, n = rest & 63;
            xpad[j] = f2b(n < NIN ? x[(b * L_ + l) * NIN + n] : 0.0f);
        }
    }
}

extern "C" void kernel_launch(void* const* d_in, const int* in_sizes, int n_in,
                              void* d_out, int out_size, void* d_ws, size_t ws_size,
                              hipStream_t stream)
{
    (void)in_sizes; (void)n_in; (void)out_size; (void)ws_size;
    const float* x    = (const float*)d_in[0];
    const float* Wih0 = (const float*)d_in[1];
    const float* Whh0 = (const float*)d_in[2];
    const float* bih0 = (const float*)d_in[3];
    const float* bhh0 = (const float*)d_in[4];
    const float* Wih1 = (const float*)d_in[5];
    const float* Whh1 = (const float*)d_in[6];
    const float* bih1 = (const float*)d_in[7];
    const float* bhh1 = (const float*)d_in[8];
    const float* Wdih = (const float*)d_in[9];
    const float* Wdhh = (const float*)d_in[10];
    const float* bihd = (const float*)d_in[11];
    const float* bhhd = (const float*)d_in[12];
    const float* Wfc  = (const float*)d_in[13];
    const float* bfc  = (const float*)d_in[14];
    float* out = (float*)d_out;

    char* ws = (char*)d_ws;
    float* c0    = (float*)(ws + 0);
    float* c1    = (float*)(ws + 524288);
    u16*   h0a   = (u16*)(ws + 1048576);
    u16*   h1a   = (u16*)(ws + 1310720);
    // zero region ends at 1572864
    u16*   h0b   = (u16*)(ws + 1572864);
    u16*   h1b   = (u16*)(ws + 1835008);
    float* h1fa  = (float*)(ws + 2097152);
    float* h1fb  = (float*)(ws + 2621440);
    u16*   ctxb  = (u16*)(ws + 3145728);
    float* ypv   = (float*)(ws + 3407872);
    u16*   Wih0p = (u16*)(ws + 3408896);
    u16*   Whh0b = (u16*)(ws + 3671040);
    u16*   Wih1b = (u16*)(ws + 5768192);
    u16*   Whh1b = (u16*)(ws + 7865344);
    u16*   Wdihb = (u16*)(ws + 9962496);
    u16*   Wdhhb = (u16*)(ws + 12059648);
    float* w0col = (float*)(ws + 14156800);
    float* bias0 = (float*)(ws + 14164992);
    float* bias1 = (float*)(ws + 14173184);
    float* biasd = (float*)(ws + 14181376);
    u16*   xpad  = (u16*)(ws + 14189568);
    u16*   E     = (u16*)(ws + 25199616);
    // total workspace use: 113,280,000 bytes

    hipMemsetAsync(d_ws, 0, 1572864, stream);  // c0, c1, h0[0], h1[0] = 0

    prep_kernel<<<512, 256, 0, stream>>>(x, Wih0, Whh0, bih0, bhh0,
        Wih1, Whh1, bih1, bhh1, Wdih, Wdhh, bihd, bhhd,
        Wih0p, Whh0b, Wih1b, Whh1b, Wdihb, Wdhhb, w0col, bias0, bias1, biasd, xpad);

    for (int tau = 0; tau <= L_; ++tau)
        enc_step2_kernel<<<32, 256, 0, stream>>>(xpad, Wih0p, Whh0b, bias0,
            Wih1b, Whh1b, bias1, h0a, h0b, c0, h1a, h1b, h1fa, h1fb, c1, E, tau);

    for (int t = 0; t < PL_; ++t) {
        attn_step_kernel<<<256, 256, 0, stream>>>((t & 1) ? h1fb : h1fa, E,
            Wfc, bfc, ctxb, ypv, out, t);
        dec_step2_kernel<<<16, 256, 0, stream>>>(ctxb, ypv, Wdihb, Wdhhb,
            biasd, w0col, h1a, h1b, h1fa, h1fb, c1, t);
    }
    attn_step_kernel<<<256, 256, 0, stream>>>(h1fa, E, Wfc, bfc, ctxb, ypv, out, PL_);
}

// Round 10
// 27980.286 us; speedup vs baseline: 1.7857x; 1.7857x over previous
//
#include <hip/hip_runtime.h>
#include <hip/hip_bf16.h>

#define B_   256
#define L_   336
#define NIN  8
#define H_   512
#define PL_  96
#define KC   64
#define BT   32
#define GT   128

typedef unsigned short u16;
typedef __attribute__((ext_vector_type(8))) short short8;
typedef __attribute__((ext_vector_type(4))) float f32x4;

__device__ __forceinline__ float sigm(float x)   { return 1.0f / (1.0f + __expf(-x)); }
__device__ __forceinline__ float tanhf_(float x) { return 1.0f - 2.0f / (1.0f + __expf(2.0f * x)); }
__device__ __forceinline__ u16 f2b(float f) {
    __hip_bfloat16 h = __float2bfloat16(f);
    return __builtin_bit_cast(u16, h);
}
__device__ __forceinline__ float b2f(u16 u) {
    union { unsigned int i; float f; } v; v.i = ((unsigned int)u) << 16; return v.f;
}

struct Seg { const u16* src; int stride; const u16* W; int nch; int ldw; };

// Double-buffered staging (software pipeline): chunk c+2's global loads are
// issued while chunk c computes, hiding the ~500-900cy L2/LLC latency that
// dominated the baseline's serial chunk chain. Index math = verified baseline.
struct SMP {
    u16   in_s[2][BT][KC + 8];     // 9.2 KB
    u16   w_s[2][GT][KC + 8];      // 36.9 KB
    float g_s[GT][BT + 1];         // 16.9 KB   -> 63.1 KB total
};

__device__ void gates_gemm_cell(const Seg* segs,
    const float* __restrict__ bias, const float* __restrict__ w0col,
    const float* __restrict__ yprev,
    float* __restrict__ cbuf, u16* __restrict__ hbf_out, float* __restrict__ hf_out,
    u16* __restrict__ Ebuf, int te, int batch0, int j0, SMP& sm)
{
    const int tid = threadIdx.x;
    const int wv = tid >> 6, lane = tid & 63;
    const int nch0 = segs[0].nch;
    const int N = nch0 + segs[1].nch;
    f32x4 acc[2][2] = {};

    // per-thread staging coordinates (verbatim baseline)
    const int ab = tid >> 3, akq = tid & 7;      // A: 32 rows x 8 thr
    int wgi[4], wkq[4], wrow[4];                 // W: 4 uint4 / thread
    #pragma unroll
    for (int i = 0; i < 4; ++i) {
        const int idx = tid + (i << 8);
        wgi[i] = idx >> 3; wkq[i] = idx & 7;
        wrow[i] = ((wgi[i] >> 5) << 9) + j0 + (wgi[i] & 31);   // q*512 + j0 + u
    }

    uint4 rA[2]; uint4 rW[2][4];
    auto issue = [&](int c, int slot) {
        const Seg& sg = segs[c >= nch0 ? 1 : 0];
        const int cc = c - (c >= nch0 ? nch0 : 0);
        const int k0 = cc * KC;
        rA[slot] = *((const uint4*)(sg.src + (size_t)(batch0 + ab) * sg.stride + k0) + akq);
        #pragma unroll
        for (int i = 0; i < 4; ++i)
            rW[slot][i] = *((const uint4*)(sg.W + (size_t)wrow[i] * sg.ldw + k0) + wkq[i]);
    };

    issue(0, 0);
    if (N > 1) issue(1, 1);

    for (int c = 0; c < N; ++c) {
        const int pb = c & 1;
        __syncthreads();                       // buf[pb] free (chunk c-2 consumed)
        *(uint4*)&sm.in_s[pb][ab][akq << 3] = rA[pb];
        #pragma unroll
        for (int i = 0; i < 4; ++i)
            *(uint4*)&sm.w_s[pb][wgi[i]][wkq[i] << 3] = rW[pb][i];
        if (c + 2 < N) issue(c + 2, pb);       // 2-deep prefetch
        __syncthreads();                       // buf[pb] ready
        #pragma unroll
        for (int ks = 0; ks < 2; ++ks) {
            const int kk = (ks << 5) + ((lane >> 4) << 3);
            short8 a0 = *(const short8*)&sm.in_s[pb][lane & 15][kk];
            short8 a1 = *(const short8*)&sm.in_s[pb][16 + (lane & 15)][kk];
            #pragma unroll
            for (int nt = 0; nt < 2; ++nt) {
                const int gi = (((wv << 1) + nt) << 4) + (lane & 15);
                short8 bb = *(const short8*)&sm.w_s[pb][gi][kk];
                acc[0][nt] = __builtin_amdgcn_mfma_f32_16x16x32_bf16(a0, bb, acc[0][nt], 0, 0, 0);
                acc[1][nt] = __builtin_amdgcn_mfma_f32_16x16x32_bf16(a1, bb, acc[1][nt], 0, 0, 0);
            }
        }
    }
    __syncthreads();
    // C/D layout (m89-verified): col(n)=lane&15, row(m)=(lane>>4)*4+reg
    #pragma unroll
    for (int mt = 0; mt < 2; ++mt)
        #pragma unroll
        for (int nt = 0; nt < 2; ++nt) {
            const int gi = (((wv << 1) + nt) << 4) + (lane & 15);
            const int brow = (mt << 4) + ((lane >> 4) << 2);
            #pragma unroll
            for (int r = 0; r < 4; ++r)
                sm.g_s[gi][brow + r] = acc[mt][nt][r];
        }
    __syncthreads();

    // LSTM cell: 32b x 32j = 1024 outputs, 4/thread (verbatim baseline)
    #pragma unroll
    for (int e = 0; e < 4; ++e) {
        const int idx = tid + (e << 8);
        const int b = idx >> 5, j = idx & 31;
        const int bg = batch0 + b, jg = j0 + j;
        float pre[4];
        #pragma unroll
        for (int q = 0; q < 4; ++q) {
            const int r = (q << 9) + jg;
            float v = sm.g_s[(q << 5) + j][b] + bias[r];
            if (w0col) v += yprev[bg] * w0col[r];
            pre[q] = v;
        }
        const float iv = sigm(pre[0]);
        const float fv = sigm(pre[1]);
        const float gv = tanhf_(pre[2]);
        const float ov = sigm(pre[3]);
        const size_t ci = ((size_t)bg << 9) + jg;
        const float cold = cbuf[ci];
        const float cn = fv * cold + iv * gv;
        const float hn = ov * tanhf_(cn);
        cbuf[ci] = cn;
        hbf_out[ci] = f2b(hn);
        if (hf_out) hf_out[ci] = hn;
        if (Ebuf) Ebuf[((size_t)bg * L_ + te) * H_ + jg] = f2b(hn);
    }
}

// Pipelined encoder: blocks 0..127 do L0 step tau; 128..255 do L1 step tau-1.
__global__ __launch_bounds__(256) void enc_step_kernel(
    const u16* __restrict__ xpad, const u16* __restrict__ Wih0p, const u16* __restrict__ Whh0b,
    const float* __restrict__ bias0,
    const u16* __restrict__ Wih1b, const u16* __restrict__ Whh1b, const float* __restrict__ bias1,
    u16* h0a, u16* h0b, float* c0,
    u16* h1a, u16* h1b, float* h1fa, float* h1fb, float* c1,
    u16* E, int tau)
{
    __shared__ SMP sm;
    const int bid = blockIdx.x;
    if (bid < 128) {
        if (tau >= L_) return;
        const int tb = bid & 7, th = bid >> 3;
        Seg segs[2];
        segs[0] = { xpad + tau * KC, L_ * KC, Wih0p, 1, KC };
        segs[1] = { (tau & 1) ? h0b : h0a, H_, Whh0b, 8, H_ };
        gates_gemm_cell(segs, bias0, nullptr, nullptr, c0,
                        (tau & 1) ? h0a : h0b, nullptr, nullptr, 0,
                        tb * BT, th * 32, sm);
    } else {
        if (tau == 0) return;
        const int te = tau - 1;
        const int id = bid - 128;
        const int tb = id & 7, th = id >> 3;
        Seg segs[2];
        segs[0] = { (tau & 1) ? h0b : h0a, H_, Wih1b, 8, H_ };  // ys0[te]
        segs[1] = { (te & 1) ? h1b : h1a, H_, Whh1b, 8, H_ };
        gates_gemm_cell(segs, bias1, nullptr, nullptr, c1,
                        (te & 1) ? h1a : h1b, (te & 1) ? h1fa : h1fb, E, te,
                        tb * BT, th * 32, sm);
    }
}

__global__ __launch_bounds__(256) void dec_step_kernel(
    const u16* __restrict__ ctxb, const float* __restrict__ yprev,
    const u16* __restrict__ Wdihb, const u16* __restrict__ Wdhhb,
    const float* __restrict__ biasd, const float* __restrict__ w0col,
    u16* h1a, u16* h1b, float* h1fa, float* h1fb, float* c1, int t)
{
    __shared__ SMP sm;
    const int bid = blockIdx.x;
    const int tb = bid & 7, th = bid >> 3;
    Seg segs[2];
    segs[0] = { ctxb, H_, Wdihb, 8, H_ };
    segs[1] = { (t & 1) ? h1b : h1a, H_, Wdhhb, 8, H_ };
    gates_gemm_cell(segs, biasd, w0col, yprev, c1,
                    (t & 1) ? h1a : h1b, (t & 1) ? h1fa : h1fb, nullptr, 0,
                    tb * BT, th * 32, sm);
}

// One block per batch row. y_{step-1} = h.Wfc + b, then flash-style attention
// over E with one-tile register prefetch (verified inside the round-7 fused
// kernel). step==PL_: y only.
__global__ __launch_bounds__(256) void attn_step_kernel(
    const float* __restrict__ hf, const u16* __restrict__ E,
    const float* __restrict__ Wfc, const float* __restrict__ bfc,
    u16* __restrict__ ctxb, float* __restrict__ yprev,
    float* __restrict__ out, int step)
{
    __shared__ float hs[H_];
    __shared__ float red[256];
    __shared__ u16 Es[48 * H_];
    __shared__ float scores[48];
    const int tid = threadIdx.x;
    const int b = blockIdx.x;

    hs[tid]       = hf[((size_t)b << 9) + tid];
    hs[tid + 256] = hf[((size_t)b << 9) + tid + 256];
    __syncthreads();

    float p = hs[tid] * Wfc[tid] + hs[tid + 256] * Wfc[tid + 256];
    red[tid] = p;
    __syncthreads();
    for (int s = 128; s > 0; s >>= 1) {
        if (tid < s) red[tid] += red[tid + s];
        __syncthreads();
    }
    if (tid == 0) {
        if (step > 0) {
            float y = red[0] + bfc[0];
            yprev[b] = y;
            out[b * PL_ + (step - 1)] = y;
        } else {
            yprev[b] = 0.0f;   // reference: y0 = zeros
        }
    }
    if (step == PL_) return;   // final launch: y only

    const int wv = tid >> 6, lane = tid & 63;
    float m = -1e30f, d = 0.0f, c0a = 0.0f, c1a = 0.0f;
    const int k0 = tid, k1 = tid + 256;
    const uint4* Ebase = (const uint4*)(E + (((size_t)b * L_) << 9));
    uint4 pre[12];
    #pragma unroll
    for (int i = 0; i < 12; ++i) pre[i] = Ebase[tid + (i << 8)];

    for (int l0 = 0; l0 < L_; l0 += 48) {
        __syncthreads();
        {
            uint4* dst = (uint4*)Es;
            #pragma unroll
            for (int i = 0; i < 12; ++i) dst[tid + (i << 8)] = pre[i];
        }
        __syncthreads();
        if (l0 + 48 < L_) {
            const uint4* nx = Ebase + ((size_t)(l0 + 48) << 6);
            #pragma unroll
            for (int i = 0; i < 12; ++i) pre[i] = nx[tid + (i << 8)];
        }
        #pragma unroll
        for (int s = 0; s < 12; ++s) {
            const int l = wv * 12 + s;
            const u16* er = &Es[(l << 9) + (lane << 3)];
            float acc = 0.f;
            #pragma unroll
            for (int j = 0; j < 8; ++j)
                acc += hs[(lane << 3) + j] * b2f(er[j]);
            #pragma unroll
            for (int off = 32; off > 0; off >>= 1)
                acc += __shfl_xor(acc, off);
            if (lane == 0) scores[l] = acc;
        }
        __syncthreads();
        float mc = m;
        #pragma unroll
        for (int l = 0; l < 48; ++l) mc = fmaxf(mc, scores[l]);
        const float alpha = __expf(m - mc);
        d *= alpha; c0a *= alpha; c1a *= alpha;
        for (int l = 0; l < 48; ++l) {
            const float pl = __expf(scores[l] - mc);
            d += pl;
            c0a += pl * b2f(Es[(l << 9) + k0]);
            c1a += pl * b2f(Es[(l << 9) + k1]);
        }
        m = mc;
    }
    const float inv = 1.0f / d;
    ctxb[((size_t)b << 9) + k0] = f2b(c0a * inv);
    ctxb[((size_t)b << 9) + k1] = f2b(c1a * inv);
}

// One-time (per call) weight conversion fp32->bf16, bias fusion, x padding to K=64.
__global__ __launch_bounds__(256) void prep_kernel(
    const float* __restrict__ x,
    const float* __restrict__ Wih0, const float* __restrict__ Whh0,
    const float* __restrict__ bih0, const float* __restrict__ bhh0,
    const float* __restrict__ Wih1, const float* __restrict__ Whh1,
    const float* __restrict__ bih1, const float* __restrict__ bhh1,
    const float* __restrict__ Wdih, const float* __restrict__ Wdhh,
    const float* __restrict__ bihd, const float* __restrict__ bhhd,
    u16* Wih0p, u16* Whh0b, u16* Wih1b, u16* Whh1b, u16* Wdihb, u16* Wdhhb,
    float* w0col, float* bias0, float* bias1, float* biasd, u16* xpad)
{
    const long E0 = 131072;
    const long E1 = E0 + 1048576;
    const long E2 = E1 + 1048576;
    const long E3 = E2 + 1048576;
    const long E4 = E3 + 1048576;
    const long E5 = E4 + 1048576;
    const long E6 = E5 + 2048;
    const long E7 = E6 + 2048;
    const long E8 = E7 + 2048;
    const long E9 = E8 + 2048;
    const long E10 = E9 + (long)B_ * L_ * KC;
    for (long idx = (long)blockIdx.x * 256 + threadIdx.x; idx < E10;
         idx += (long)gridDim.x * 256) {
        if (idx < E0) {
            long r = idx >> 6, cc = idx & 63;
            Wih0p[idx] = f2b(cc < NIN ? Wih0[(r << 3) + cc] : 0.0f);
        } else if (idx < E1) { long j = idx - E0; Whh0b[j] = f2b(Whh0[j]);
        } else if (idx < E2) { long j = idx - E1; Wih1b[j] = f2b(Wih1[j]);
        } else if (idx < E3) { long j = idx - E2; Whh1b[j] = f2b(Whh1[j]);
        } else if (idx < E4) {
            long j = idx - E3; long r = j >> 9, cc = j & 511;
            Wdihb[j] = f2b(Wdih[r * 513 + 1 + cc]);
        } else if (idx < E5) { long j = idx - E4; Wdhhb[j] = f2b(Wdhh[j]);
        } else if (idx < E6) { long j = idx - E5; w0col[j] = Wdih[j * 513];
        } else if (idx < E7) { long j = idx - E6; bias0[j] = bih0[j] + bhh0[j];
        } else if (idx < E8) { long j = idx - E7; bias1[j] = bih1[j] + bhh1[j];
        } else if (idx < E9) { long j = idx - E8; biasd[j] = bihd[j] + bhhd[j];
        } else {
            long j = idx - E9;
            long b = j / (L_ * KC);
            long rest = j - b * (L_ * KC);
            long l = rest >> 6, n = rest & 63;
            xpad[j] = f2b(n < NIN ? x[(b * L_ + l) * NIN + n] : 0.0f);
        }
    }
}

extern "C" void kernel_launch(void* const* d_in, const int* in_sizes, int n_in,
                              void* d_out, int out_size, void* d_ws, size_t ws_size,
                              hipStream_t stream)
{
    (void)in_sizes; (void)n_in; (void)out_size; (void)ws_size;
    const float* x    = (const float*)d_in[0];
    const float* Wih0 = (const float*)d_in[1];
    const float* Whh0 = (const float*)d_in[2];
    const float* bih0 = (const float*)d_in[3];
    const float* bhh0 = (const float*)d_in[4];
    const float* Wih1 = (const float*)d_in[5];
    const float* Whh1 = (const float*)d_in[6];
    const float* bih1 = (const float*)d_in[7];
    const float* bhh1 = (const float*)d_in[8];
    const float* Wdih = (const float*)d_in[9];
    const float* Wdhh = (const float*)d_in[10];
    const float* bihd = (const float*)d_in[11];
    const float* bhhd = (const float*)d_in[12];
    const float* Wfc  = (const float*)d_in[13];
    const float* bfc  = (const float*)d_in[14];
    float* out = (float*)d_out;

    char* ws = (char*)d_ws;
    float* c0    = (float*)(ws + 0);
    float* c1    = (float*)(ws + 524288);
    u16*   h0a   = (u16*)(ws + 1048576);
    u16*   h1a   = (u16*)(ws + 1310720);
    // zero region ends at 1572864
    u16*   h0b   = (u16*)(ws + 1572864);
    u16*   h1b   = (u16*)(ws + 1835008);
    float* h1fa  = (float*)(ws + 2097152);
    float* h1fb  = (float*)(ws + 2621440);
    u16*   ctxb  = (u16*)(ws + 3145728);
    float* ypv   = (float*)(ws + 3407872);
    u16*   Wih0p = (u16*)(ws + 3408896);
    u16*   Whh0b = (u16*)(ws + 3671040);
    u16*   Wih1b = (u16*)(ws + 5768192);
    u16*   Whh1b = (u16*)(ws + 7865344);
    u16*   Wdihb = (u16*)(ws + 9962496);
    u16*   Wdhhb = (u16*)(ws + 12059648);
    float* w0col = (float*)(ws + 14156800);
    float* bias0 = (float*)(ws + 14164992);
    float* bias1 = (float*)(ws + 14173184);
    float* biasd = (float*)(ws + 14181376);
    u16*   xpad  = (u16*)(ws + 14189568);
    u16*   E     = (u16*)(ws + 25199616);
    // total workspace use: 113,280,000 bytes

    hipMemsetAsync(d_ws, 0, 1572864, stream);  // c0, c1, h0[0], h1[0] = 0

    prep_kernel<<<512, 256, 0, stream>>>(x, Wih0, Whh0, bih0, bhh0,
        Wih1, Whh1, bih1, bhh1, Wdih, Wdhh, bihd, bhhd,
        Wih0p, Whh0b, Wih1b, Whh1b, Wdihb, Wdhhb, w0col, bias0, bias1, biasd, xpad);

    for (int tau = 0; tau <= L_; ++tau)
        enc_step_kernel<<<256, 256, 0, stream>>>(xpad, Wih0p, Whh0b, bias0,
            Wih1b, Whh1b, bias1, h0a, h0b, c0, h1a, h1b, h1fa, h1fb, c1, E, tau);

    for (int t = 0; t < PL_; ++t) {
        attn_step_kernel<<<256, 256, 0, stream>>>((t & 1) ? h1fb : h1fa, E,
            Wfc, bfc, ctxb, ypv, out, t);
        dec_step_kernel<<<128, 256, 0, stream>>>(ctxb, ypv, Wdihb, Wdhhb,
            biasd, w0col, h1a, h1b, h1fa, h1fb, c1, t);
    }
    attn_step_kernel<<<256, 256, 0, stream>>>(h1fa, E, Wfc, bfc, ctxb, ypv, out, PL_);
}

// Round 12
// 22406.882 us; speedup vs baseline: 2.2299x; 1.2487x over previous
//
#include <hip/hip_runtime.h>
#include <hip/hip_bf16.h>

#define B_   256
#define L_   336
#define NIN  8
#define H_   512
#define PL_  96
#define KC   64
#define BT   32
#define GT   128

typedef unsigned short u16;
typedef __attribute__((ext_vector_type(8))) short short8;
typedef __attribute__((ext_vector_type(4))) float f32x4;

__device__ __forceinline__ float sigm(float x)   { return 1.0f / (1.0f + __expf(-x)); }
__device__ __forceinline__ float tanhf_(float x) { return 1.0f - 2.0f / (1.0f + __expf(2.0f * x)); }
__device__ __forceinline__ u16 f2b(float f) {
    __hip_bfloat16 h = __float2bfloat16(f);
    return __builtin_bit_cast(u16, h);
}
__device__ __forceinline__ float b2f(u16 u) {
    union { unsigned int i; float f; } v; v.i = ((unsigned int)u) << 16; return v.f;
}

struct Seg { const u16* src; int stride; const u16* W; int nch; int ldw; };

// Double-buffered staging, scratch-free: named register slots (rA0/rW0,
// rA1/rW1), hand-unrolled x2 loop so ALL register indices are compile-time
// (rule #20: runtime-indexed arrays go to scratch — that was round-10's 2x
// regression). One barrier per chunk (dbuf schedule).
struct SMP {
    u16   in_s[2][BT][KC + 8];     // 9.2 KB
    u16   w_s[2][GT][KC + 8];      // 36.9 KB
    float g_s[GT][BT + 1];         // 16.9 KB   -> 61.5 KB total
};

__device__ void gates_gemm_cell(const Seg* segs,
    const float* __restrict__ bias, const float* __restrict__ w0col,
    const float* __restrict__ yprev,
    float* __restrict__ cbuf, u16* __restrict__ hbf_out, float* __restrict__ hf_out,
    u16* __restrict__ Ebuf, int te, int batch0, int j0, SMP& sm)
{
    const int tid = threadIdx.x;
    const int wv = tid >> 6, lane = tid & 63;
    const int nch0 = segs[0].nch;
    const int N = nch0 + segs[1].nch;
    // unpack Seg fields to scalars (static indices only)
    const u16* src0 = segs[0].src; const int str0 = segs[0].stride;
    const u16* Wp0  = segs[0].W;   const int ldw0 = segs[0].ldw;
    const u16* src1 = segs[1].src; const int str1 = segs[1].stride;
    const u16* Wp1  = segs[1].W;   const int ldw1 = segs[1].ldw;
    f32x4 acc[2][2] = {};

    // per-thread staging coordinates (verbatim baseline)
    const int ab = tid >> 3, akq = tid & 7;      // A: 32 rows x 8 thr
    int wgi[4], wkq[4], wrow[4];                 // W: 4 uint4 / thread
    #pragma unroll
    for (int i = 0; i < 4; ++i) {
        const int idx = tid + (i << 8);
        wgi[i] = idx >> 3; wkq[i] = idx & 7;
        wrow[i] = ((wgi[i] >> 5) << 9) + j0 + (wgi[i] & 31);   // q*512 + j0 + u
    }

    uint4 rA0, rW0[4], rA1, rW1[4];

#define ISSUE(C, A, W) { \
        const bool s1_ = (C) >= nch0; \
        const u16* asrc_ = s1_ ? src1 : src0; \
        const int  astr_ = s1_ ? str1 : str0; \
        const u16* wsrc_ = s1_ ? Wp1 : Wp0; \
        const int  wld_  = s1_ ? ldw1 : ldw0; \
        const int  k0_   = ((C) - (s1_ ? nch0 : 0)) * KC; \
        A = *((const uint4*)(asrc_ + (size_t)(batch0 + ab) * astr_ + k0_) + akq); \
        _Pragma("unroll") \
        for (int i_ = 0; i_ < 4; ++i_) \
            W[i_] = *((const uint4*)(wsrc_ + (size_t)wrow[i_] * wld_ + k0_) + wkq[i_]); \
    }

#define WRITE(PB, A, W) { \
        *(uint4*)&sm.in_s[PB][ab][akq << 3] = A; \
        _Pragma("unroll") \
        for (int i_ = 0; i_ < 4; ++i_) \
            *(uint4*)&sm.w_s[PB][wgi[i_]][wkq[i_] << 3] = W[i_]; \
    }

#define COMPUTE(PB) { \
        _Pragma("unroll") \
        for (int ks = 0; ks < 2; ++ks) { \
            const int kk = (ks << 5) + ((lane >> 4) << 3); \
            short8 a0 = *(const short8*)&sm.in_s[PB][lane & 15][kk]; \
            short8 a1 = *(const short8*)&sm.in_s[PB][16 + (lane & 15)][kk]; \
            _Pragma("unroll") \
            for (int nt = 0; nt < 2; ++nt) { \
                const int gi = (((wv << 1) + nt) << 4) + (lane & 15); \
                short8 bb = *(const short8*)&sm.w_s[PB][gi][kk]; \
                acc[0][nt] = __builtin_amdgcn_mfma_f32_16x16x32_bf16(a0, bb, acc[0][nt], 0, 0, 0); \
                acc[1][nt] = __builtin_amdgcn_mfma_f32_16x16x32_bf16(a1, bb, acc[1][nt], 0, 0, 0); \
            } \
        } \
    }

    // prologue: 2-deep register prefetch, stage chunk 0 into buf 0
    ISSUE(0, rA0, rW0);
    if (N > 1) ISSUE(1, rA1, rW1);
    WRITE(0, rA0, rW0);
    if (2 < N) ISSUE(2, rA0, rW0);
    __syncthreads();                 // buf0 ready

    int c = 0;
    for (;;) {
        COMPUTE(0);                  // chunk c (even slot)
        if (c + 1 >= N) break;
        WRITE(1, rA1, rW1);          // chunk c+1 -> buf1 (buf1's last reader
                                     // finished before the previous barrier)
        if (c + 3 < N) ISSUE(c + 3, rA1, rW1);
        __syncthreads();             // buf1 ready, all done reading buf0
        COMPUTE(1);                  // chunk c+1 (odd slot)
        if (c + 2 >= N) break;
        WRITE(0, rA0, rW0);          // chunk c+2 -> buf0
        if (c + 4 < N) ISSUE(c + 4, rA0, rW0);
        __syncthreads();
        c += 2;
    }
#undef ISSUE
#undef WRITE
#undef COMPUTE

    __syncthreads();
    // C/D layout (m89-verified): col(n)=lane&15, row(m)=(lane>>4)*4+reg
    #pragma unroll
    for (int mt = 0; mt < 2; ++mt)
        #pragma unroll
        for (int nt = 0; nt < 2; ++nt) {
            const int gi = (((wv << 1) + nt) << 4) + (lane & 15);
            const int brow = (mt << 4) + ((lane >> 4) << 2);
            #pragma unroll
            for (int r = 0; r < 4; ++r)
                sm.g_s[gi][brow + r] = acc[mt][nt][r];
        }
    __syncthreads();

    // LSTM cell: 32b x 32j = 1024 outputs, 4/thread (verbatim baseline)
    #pragma unroll
    for (int e = 0; e < 4; ++e) {
        const int idx = tid + (e << 8);
        const int b = idx >> 5, j = idx & 31;
        const int bg = batch0 + b, jg = j0 + j;
        float pre[4];
        #pragma unroll
        for (int q = 0; q < 4; ++q) {
            const int r = (q << 9) + jg;
            float v = sm.g_s[(q << 5) + j][b] + bias[r];
            if (w0col) v += yprev[bg] * w0col[r];
            pre[q] = v;
        }
        const float iv = sigm(pre[0]);
        const float fv = sigm(pre[1]);
        const float gv = tanhf_(pre[2]);
        const float ov = sigm(pre[3]);
        const size_t ci = ((size_t)bg << 9) + jg;
        const float cold = cbuf[ci];
        const float cn = fv * cold + iv * gv;
        const float hn = ov * tanhf_(cn);
        cbuf[ci] = cn;
        hbf_out[ci] = f2b(hn);
        if (hf_out) hf_out[ci] = hn;
        if (Ebuf) Ebuf[((size_t)bg * L_ + te) * H_ + jg] = f2b(hn);
    }
}

// Pipelined encoder: blocks 0..127 do L0 step tau; 128..255 do L1 step tau-1.
__global__ __launch_bounds__(256) void enc_step_kernel(
    const u16* __restrict__ xpad, const u16* __restrict__ Wih0p, const u16* __restrict__ Whh0b,
    const float* __restrict__ bias0,
    const u16* __restrict__ Wih1b, const u16* __restrict__ Whh1b, const float* __restrict__ bias1,
    u16* h0a, u16* h0b, float* c0,
    u16* h1a, u16* h1b, float* h1fa, float* h1fb, float* c1,
    u16* E, int tau)
{
    __shared__ SMP sm;
    const int bid = blockIdx.x;
    if (bid < 128) {
        if (tau >= L_) return;
        const int tb = bid & 7, th = bid >> 3;
        Seg segs[2];
        segs[0] = { xpad + tau * KC, L_ * KC, Wih0p, 1, KC };
        segs[1] = { (tau & 1) ? h0b : h0a, H_, Whh0b, 8, H_ };
        gates_gemm_cell(segs, bias0, nullptr, nullptr, c0,
                        (tau & 1) ? h0a : h0b, nullptr, nullptr, 0,
                        tb * BT, th * 32, sm);
    } else {
        if (tau == 0) return;
        const int te = tau - 1;
        const int id = bid - 128;
        const int tb = id & 7, th = id >> 3;
        Seg segs[2];
        segs[0] = { (tau & 1) ? h0b : h0a, H_, Wih1b, 8, H_ };  // ys0[te]
        segs[1] = { (te & 1) ? h1b : h1a, H_, Whh1b, 8, H_ };
        gates_gemm_cell(segs, bias1, nullptr, nullptr, c1,
                        (te & 1) ? h1a : h1b, (te & 1) ? h1fa : h1fb, E, te,
                        tb * BT, th * 32, sm);
    }
}

__global__ __launch_bounds__(256) void dec_step_kernel(
    const u16* __restrict__ ctxb, const float* __restrict__ yprev,
    const u16* __restrict__ Wdihb, const u16* __restrict__ Wdhhb,
    const float* __restrict__ biasd, const float* __restrict__ w0col,
    u16* h1a, u16* h1b, float* h1fa, float* h1fb, float* c1, int t)
{
    __shared__ SMP sm;
    const int bid = blockIdx.x;
    const int tb = bid & 7, th = bid >> 3;
    Seg segs[2];
    segs[0] = { ctxb, H_, Wdihb, 8, H_ };
    segs[1] = { (t & 1) ? h1b : h1a, H_, Wdhhb, 8, H_ };
    gates_gemm_cell(segs, biasd, w0col, yprev, c1,
                    (t & 1) ? h1a : h1b, (t & 1) ? h1fa : h1fb, nullptr, 0,
                    tb * BT, th * 32, sm);
}

// One block per batch row. y_{step-1} = h.Wfc + b, then flash-style attention
// over E with one-tile register prefetch (verified in rounds 7/10).
// step==PL_: y only.
__global__ __launch_bounds__(256) void attn_step_kernel(
    const float* __restrict__ hf, const u16* __restrict__ E,
    const float* __restrict__ Wfc, const float* __restrict__ bfc,
    u16* __restrict__ ctxb, float* __restrict__ yprev,
    float* __restrict__ out, int step)
{
    __shared__ float hs[H_];
    __shared__ float red[256];
    __shared__ u16 Es[48 * H_];
    __shared__ float scores[48];
    const int tid = threadIdx.x;
    const int b = blockIdx.x;

    hs[tid]       = hf[((size_t)b << 9) + tid];
    hs[tid + 256] = hf[((size_t)b << 9) + tid + 256];
    __syncthreads();

    float p = hs[tid] * Wfc[tid] + hs[tid + 256] * Wfc[tid + 256];
    red[tid] = p;
    __syncthreads();
    for (int s = 128; s > 0; s >>= 1) {
        if (tid < s) red[tid] += red[tid + s];
        __syncthreads();
    }
    if (tid == 0) {
        if (step > 0) {
            float y = red[0] + bfc[0];
            yprev[b] = y;
            out[b * PL_ + (step - 1)] = y;
        } else {
            yprev[b] = 0.0f;   // reference: y0 = zeros
        }
    }
    if (step == PL_) return;   // final launch: y only

    const int wv = tid >> 6, lane = tid & 63;
    float m = -1e30f, d = 0.0f, c0a = 0.0f, c1a = 0.0f;
    const int k0 = tid, k1 = tid + 256;
    const uint4* Ebase = (const uint4*)(E + (((size_t)b * L_) << 9));
    uint4 pre[12];
    #pragma unroll
    for (int i = 0; i < 12; ++i) pre[i] = Ebase[tid + (i << 8)];

    for (int l0 = 0; l0 < L_; l0 += 48) {
        __syncthreads();
        {
            uint4* dst = (uint4*)Es;
            #pragma unroll
            for (int i = 0; i < 12; ++i) dst[tid + (i << 8)] = pre[i];
        }
        __syncthreads();
        if (l0 + 48 < L_) {
            const uint4* nx = Ebase + ((size_t)(l0 + 48) << 6);
            #pragma unroll
            for (int i = 0; i < 12; ++i) pre[i] = nx[tid + (i << 8)];
        }
        #pragma unroll
        for (int s = 0; s < 12; ++s) {
            const int l = wv * 12 + s;
            const u16* er = &Es[(l << 9) + (lane << 3)];
            float acc = 0.f;
            #pragma unroll
            for (int j = 0; j < 8; ++j)
                acc += hs[(lane << 3) + j] * b2f(er[j]);
            #pragma unroll
            for (int off = 32; off > 0; off >>= 1)
                acc += __shfl_xor(acc, off);
            if (lane == 0) scores[l] = acc;
        }
        __syncthreads();
        float mc = m;
        #pragma unroll
        for (int l = 0; l < 48; ++l) mc = fmaxf(mc, scores[l]);
        const float alpha = __expf(m - mc);
        d *= alpha; c0a *= alpha; c1a *= alpha;
        for (int l = 0; l < 48; ++l) {
            const float pl = __expf(scores[l] - mc);
            d += pl;
            c0a += pl * b2f(Es[(l << 9) + k0]);
            c1a += pl * b2f(Es[(l << 9) + k1]);
        }
        m = mc;
    }
    const float inv = 1.0f / d;
    ctxb[((size_t)b << 9) + k0] = f2b(c0a * inv);
    ctxb[((size_t)b << 9) + k1] = f2b(c1a * inv);
}

// One-time (per call) weight conversion fp32->bf16, bias fusion, x padding to K=64.
__global__ __launch_bounds__(256) void prep_kernel(
    const float* __restrict__ x,
    const float* __restrict__ Wih0, const float* __restrict__ Whh0,
    const float* __restrict__ bih0, const float* __restrict__ bhh0,
    const float* __restrict__ Wih1, const float* __restrict__ Whh1,
    const float* __restrict__ bih1, const float* __restrict__ bhh1,
    const float* __restrict__ Wdih, const float* __restrict__ Wdhh,
    const float* __restrict__ bihd, const float* __restrict__ bhhd,
    u16* Wih0p, u16* Whh0b, u16* Wih1b, u16* Whh1b, u16* Wdihb, u16* Wdhhb,
    float* w0col, float* bias0, float* bias1, float* biasd, u16* xpad)
{
    const long E0 = 131072;
    const long E1 = E0 + 1048576;
    const long E2 = E1 + 1048576;
    const long E3 = E2 + 1048576;
    const long E4 = E3 + 1048576;
    const long E5 = E4 + 1048576;
    const long E6 = E5 + 2048;
    const long E7 = E6 + 2048;
    const long E8 = E7 + 2048;
    const long E9 = E8 + 2048;
    const long E10 = E9 + (long)B_ * L_ * KC;
    for (long idx = (long)blockIdx.x * 256 + threadIdx.x; idx < E10;
         idx += (long)gridDim.x * 256) {
        if (idx < E0) {
            long r = idx >> 6, cc = idx & 63;
            Wih0p[idx] = f2b(cc < NIN ? Wih0[(r << 3) + cc] : 0.0f);
        } else if (idx < E1) { long j = idx - E0; Whh0b[j] = f2b(Whh0[j]);
        } else if (idx < E2) { long j = idx - E1; Wih1b[j] = f2b(Wih1[j]);
        } else if (idx < E3) { long j = idx - E2; Whh1b[j] = f2b(Whh1[j]);
        } else if (idx < E4) {
            long j = idx - E3; long r = j >> 9, cc = j & 511;
            Wdihb[j] = f2b(Wdih[r * 513 + 1 + cc]);
        } else if (idx < E5) { long j = idx - E4; Wdhhb[j] = f2b(Wdhh[j]);
        } else if (idx < E6) { long j = idx - E5; w0col[j] = Wdih[j * 513];
        } else if (idx < E7) { long j = idx - E6; bias0[j] = bih0[j] + bhh0[j];
        } else if (idx < E8) { long j = idx - E7; bias1[j] = bih1[j] + bhh1[j];
        } else if (idx < E9) { long j = idx - E8; biasd[j] = bihd[j] + bhhd[j];
        } else {
            long j = idx - E9;
            long b = j / (L_ * KC);
            long rest = j - b * (L_ * KC);
            long l = rest >> 6, n = rest & 63;
            xpad[j] = f2b(n < NIN ? x[(b * L_ + l) * NIN + n] : 0.0f);
        }
    }
}

extern "C" void kernel_launch(void* const* d_in, const int* in_sizes, int n_in,
                              void* d_out, int out_size, void* d_ws, size_t ws_size,
                              hipStream_t stream)
{
    (void)in_sizes; (void)n_in; (void)out_size; (void)ws_size;
    const float* x    = (const float*)d_in[0];
    const float* Wih0 = (const float*)d_in[1];
    const float* Whh0 = (const float*)d_in[2];
    const float* bih0 = (const float*)d_in[3];
    const float* bhh0 = (const float*)d_in[4];
    const float* Wih1 = (const float*)d_in[5];
    const float* Whh1 = (const float*)d_in[6];
    const float* bih1 = (const float*)d_in[7];
    const float* bhh1 = (const float*)d_in[8];
    const float* Wdih = (const float*)d_in[9];
    const float* Wdhh = (const float*)d_in[10];
    const float* bihd = (const float*)d_in[11];
    const float* bhhd = (const float*)d_in[12];
    const float* Wfc  = (const float*)d_in[13];
    const float* bfc  = (const float*)d_in[14];
    float* out = (float*)d_out;

    char* ws = (char*)d_ws;
    float* c0    = (float*)(ws + 0);
    float* c1    = (float*)(ws + 524288);
    u16*   h0a   = (u16*)(ws + 1048576);
    u16*   h1a   = (u16*)(ws + 1310720);
    // zero region ends at 1572864
    u16*   h0b   = (u16*)(ws + 1572864);
    u16*   h1b   = (u16*)(ws + 1835008);
    float* h1fa  = (float*)(ws + 2097152);
    float* h1fb  = (float*)(ws + 2621440);
    u16*   ctxb  = (u16*)(ws + 3145728);
    float* ypv   = (float*)(ws + 3407872);
    u16*   Wih0p = (u16*)(ws + 3408896);
    u16*   Whh0b = (u16*)(ws + 3671040);
    u16*   Wih1b = (u16*)(ws + 5768192);
    u16*   Whh1b = (u16*)(ws + 7865344);
    u16*   Wdihb = (u16*)(ws + 9962496);
    u16*   Wdhhb = (u16*)(ws + 12059648);
    float* w0col = (float*)(ws + 14156800);
    float* bias0 = (float*)(ws + 14164992);
    float* bias1 = (float*)(ws + 14173184);
    float* biasd = (float*)(ws + 14181376);
    u16*   xpad  = (u16*)(ws + 14189568);
    u16*   E     = (u16*)(ws + 25199616);
    // total workspace use: 113,280,000 bytes

    hipMemsetAsync(d_ws, 0, 1572864, stream);  // c0, c1, h0[0], h1[0] = 0

    prep_kernel<<<512, 256, 0, stream>>>(x, Wih0, Whh0, bih0, bhh0,
        Wih1, Whh1, bih1, bhh1, Wdih, Wdhh, bihd, bhhd,
        Wih0p, Whh0b, Wih1b, Whh1b, Wdihb, Wdhhb, w0col, bias0, bias1, biasd, xpad);

    for (int tau = 0; tau <= L_; ++tau)
        enc_step_kernel<<<256, 256, 0, stream>>>(xpad, Wih0p, Whh0b, bias0,
            Wih1b, Whh1b, bias1, h0a, h0b, c0, h1a, h1b, h1fa, h1fb, c1, E, tau);

    for (int t = 0; t < PL_; ++t) {
        attn_step_kernel<<<256, 256, 0, stream>>>((t & 1) ? h1fb : h1fa, E,
            Wfc, bfc, ctxb, ypv, out, t);
        dec_step_kernel<<<128, 256, 0, stream>>>(ctxb, ypv, Wdihb, Wdhhb,
            biasd, w0col, h1a, h1b, h1fa, h1fb, c1, t);
    }
    attn_step_kernel<<<256, 256, 0, stream>>>(h1fa, E, Wfc, bfc, ctxb, ypv, out, PL_);
}

// Round 14
// 21397.153 us; speedup vs baseline: 2.3351x; 1.0472x over previous
//
#include <hip/hip_runtime.h>
#include <hip/hip_bf16.h>

#define B_   256
#define L_   336
#define NIN  8
#define H_   512
#define PL_  96
#define KC   64
#define BT   32
#define GT   128

typedef unsigned short u16;
typedef __attribute__((ext_vector_type(8))) short short8;
typedef __attribute__((ext_vector_type(4))) float f32x4;

__device__ __forceinline__ float sigm(float x)   { return 1.0f / (1.0f + __expf(-x)); }
__device__ __forceinline__ float tanhf_(float x) { return 1.0f - 2.0f / (1.0f + __expf(2.0f * x)); }
__device__ __forceinline__ u16 f2b(float f) {
    __hip_bfloat16 h = __float2bfloat16(f);
    return __builtin_bit_cast(u16, h);
}
__device__ __forceinline__ float b2f(u16 u) {
    union { unsigned int i; float f; } v; v.i = ((unsigned int)u) << 16; return v.f;
}

// KC=128 H-chunks: halves the serialized {stage -> barrier-drain -> MFMA}
// chain vs the KC=64 baseline (L0 9->5 chunks, L1/dec 16->8; barriers
// 18/32 -> 10/16 per step). Same verified stage/compute pattern per chunk —
// no prefetch/dbuf (source-level pipelining defeated by the vmcnt(0) drain
// before s_barrier; measured rounds 10/12).
// Row stride 136 elems = 68 dwords == 4 mod 32 -> same bank residue as the
// verified 72-elem baseline (2-way on wave64 = free, m136).
struct SMC {
    u16   in_s[BT][136];        // 8.7 KB
    u16   w_s[GT][136];         // 34.8 KB
    float g_s[GT][BT + 1];      // 16.9 KB  -> 60.4 KB
};

__device__ __forceinline__ void mfma_block(SMC& sm, int nks, int wv, int lane, int klo,
                                           f32x4 (&acc)[2][2])
{
    #pragma unroll 4
    for (int ks = 0; ks < nks; ++ks) {
        const int kk = (ks << 5) + klo;
        short8 a0 = *(const short8*)&sm.in_s[lane & 15][kk];
        short8 a1 = *(const short8*)&sm.in_s[16 + (lane & 15)][kk];
        #pragma unroll
        for (int nt = 0; nt < 2; ++nt) {
            const int gi = (((wv << 1) + nt) << 4) + (lane & 15);
            short8 bb = *(const short8*)&sm.w_s[gi][kk];
            acc[0][nt] = __builtin_amdgcn_mfma_f32_16x16x32_bf16(a0, bb, acc[0][nt], 0, 0, 0);
            acc[1][nt] = __builtin_amdgcn_mfma_f32_16x16x32_bf16(a1, bb, acc[1][nt], 0, 0, 0);
        }
    }
}

// one 128-wide chunk: stage A(32x128) + W(128x128), barrier, 4x MFMA step
__device__ __forceinline__ void chunk128(SMC& sm, const u16* __restrict__ src, int stride,
    const u16* __restrict__ W, int ldw, int k0, int batch0, int j0,
    int tid, int wv, int lane, int klo, f32x4 (&acc)[2][2])
{
    __syncthreads();
    #pragma unroll
    for (int i = 0; i < 2; ++i) {      // A: 512 uint4
        const int idx = tid + (i << 8);
        const int row = idx >> 4, kq = idx & 15;
        *(uint4*)&sm.in_s[row][kq << 3] =
            *((const uint4*)(src + (size_t)(batch0 + row) * stride + k0) + kq);
    }
    #pragma unroll
    for (int i = 0; i < 8; ++i) {      // W: 2048 uint4
        const int idx = tid + (i << 8);
        const int gi = idx >> 4, kq = idx & 15;
        const int row = ((gi >> 5) << 9) + j0 + (gi & 31);   // q*512 + j0 + u
        *(uint4*)&sm.w_s[gi][kq << 3] =
            *((const uint4*)(W + (size_t)row * ldw + k0) + kq);
    }
    __syncthreads();
    mfma_block(sm, 4, wv, lane, klo, acc);
}

// one 64-wide chunk (the x segment) — verbatim baseline staging
__device__ __forceinline__ void chunk64(SMC& sm, const u16* __restrict__ src, int stride,
    const u16* __restrict__ W, int ldw, int batch0, int j0,
    int tid, int wv, int lane, int klo, f32x4 (&acc)[2][2])
{
    __syncthreads();
    {
        const int b = tid >> 3, kq = tid & 7;
        *(uint4*)&sm.in_s[b][kq << 3] =
            *((const uint4*)(src + (size_t)(batch0 + b) * stride) + kq);
    }
    #pragma unroll
    for (int i = 0; i < 4; ++i) {
        const int idx = tid + (i << 8);
        const int gi = idx >> 3, kq = idx & 7;
        const int row = ((gi >> 5) << 9) + j0 + (gi & 31);
        *(uint4*)&sm.w_s[gi][kq << 3] =
            *((const uint4*)(W + (size_t)row * ldw) + kq);
    }
    __syncthreads();
    mfma_block(sm, 2, wv, lane, klo, acc);
}

// gates GEMM (optional 64-wide x-seg + one/two 512-wide segs) + LSTM cell.
// Epilogue/cell math byte-identical to the verified baseline.
__device__ void gates_cell(SMC& sm,
    const u16* __restrict__ x64, int xstride, const u16* __restrict__ Wx,
    const u16* __restrict__ hA, const u16* __restrict__ WA,
    const u16* __restrict__ hB, const u16* __restrict__ WB,
    const float* __restrict__ bias, const float* __restrict__ w0col,
    const float* __restrict__ yprev,
    float* __restrict__ cbuf, u16* __restrict__ hbf_out, float* __restrict__ hf_out,
    u16* __restrict__ Ebuf, int te, int batch0, int j0)
{
    const int tid = threadIdx.x;
    const int wv = tid >> 6, lane = tid & 63;
    const int klo = (lane >> 4) << 3;
    f32x4 acc[2][2] = {};

    if (x64) chunk64(sm, x64, xstride, Wx, KC, batch0, j0, tid, wv, lane, klo, acc);
    #pragma unroll
    for (int cc = 0; cc < 4; ++cc)
        chunk128(sm, hA, H_, WA, H_, cc << 7, batch0, j0, tid, wv, lane, klo, acc);
    if (hB)
        #pragma unroll
        for (int cc = 0; cc < 4; ++cc)
            chunk128(sm, hB, H_, WB, H_, cc << 7, batch0, j0, tid, wv, lane, klo, acc);

    __syncthreads();
    // C/D layout (m89-verified): col(n)=lane&15, row(m)=(lane>>4)*4+reg
    #pragma unroll
    for (int mt = 0; mt < 2; ++mt)
        #pragma unroll
        for (int nt = 0; nt < 2; ++nt) {
            const int gi = (((wv << 1) + nt) << 4) + (lane & 15);
            const int brow = (mt << 4) + ((lane >> 4) << 2);
            #pragma unroll
            for (int r = 0; r < 4; ++r)
                sm.g_s[gi][brow + r] = acc[mt][nt][r];
        }
    __syncthreads();

    // LSTM cell: 32b x 32j = 1024 outputs, 4/thread (verbatim baseline)
    #pragma unroll
    for (int e = 0; e < 4; ++e) {
        const int idx = tid + (e << 8);
        const int b = idx >> 5, j = idx & 31;
        const int bg = batch0 + b, jg = j0 + j;
        float pre[4];
        #pragma unroll
        for (int q = 0; q < 4; ++q) {
            const int r = (q << 9) + jg;
            float v = sm.g_s[(q << 5) + j][b] + bias[r];
            if (w0col) v += yprev[bg] * w0col[r];
            pre[q] = v;
        }
        const float iv = sigm(pre[0]);
        const float fv = sigm(pre[1]);
        const float gv = tanhf_(pre[2]);
        const float ov = sigm(pre[3]);
        const size_t ci = ((size_t)bg << 9) + jg;
        const float cold = cbuf[ci];
        const float cn = fv * cold + iv * gv;
        const float hn = ov * tanhf_(cn);
        cbuf[ci] = cn;
        hbf_out[ci] = f2b(hn);
        if (hf_out) hf_out[ci] = hn;
        if (Ebuf) Ebuf[((size_t)bg * L_ + te) * H_ + jg] = f2b(hn);
    }
}

// Pipelined encoder: blocks 0..127 do L0 step tau; 128..255 do L1 step tau-1.
__global__ __launch_bounds__(256) void enc_step_kernel(
    const u16* __restrict__ xpad, const u16* __restrict__ Wih0p, const u16* __restrict__ Whh0b,
    const float* __restrict__ bias0,
    const u16* __restrict__ Wih1b, const u16* __restrict__ Whh1b, const float* __restrict__ bias1,
    u16* h0a, u16* h0b, float* c0,
    u16* h1a, u16* h1b, float* h1fa, float* h1fb, float* c1,
    u16* E, int tau)
{
    __shared__ SMC sm;
    const int bid = blockIdx.x;
    if (bid < 128) {
        if (tau >= L_) return;
        const int tb = bid & 7, th = bid >> 3;
        gates_cell(sm,
                   xpad + tau * KC, L_ * KC, Wih0p,
                   (tau & 1) ? h0b : h0a, Whh0b,
                   nullptr, nullptr,
                   bias0, nullptr, nullptr, c0,
                   (tau & 1) ? h0a : h0b, nullptr, nullptr, 0,
                   tb * BT, th * 32);
    } else {
        if (tau == 0) return;
        const int te = tau - 1;
        const int id = bid - 128;
        const int tb = id & 7, th = id >> 3;
        gates_cell(sm,
                   nullptr, 0, nullptr,
                   (tau & 1) ? h0b : h0a, Wih1b,      // ys0[te]
                   (te & 1) ? h1b : h1a, Whh1b,
                   bias1, nullptr, nullptr, c1,
                   (te & 1) ? h1a : h1b, (te & 1) ? h1fa : h1fb, E, te,
                   tb * BT, th * 32);
    }
}

__global__ __launch_bounds__(256) void dec_step_kernel(
    const u16* __restrict__ ctxb, const float* __restrict__ yprev,
    const u16* __restrict__ Wdihb, const u16* __restrict__ Wdhhb,
    const float* __restrict__ biasd, const float* __restrict__ w0col,
    u16* h1a, u16* h1b, float* h1fa, float* h1fb, float* c1, int t)
{
    __shared__ SMC sm;
    const int bid = blockIdx.x;
    const int tb = bid & 7, th = bid >> 3;
    gates_cell(sm,
               nullptr, 0, nullptr,
               ctxb, Wdihb,
               (t & 1) ? h1b : h1a, Wdhhb,
               biasd, w0col, yprev, c1,
               (t & 1) ? h1a : h1b, (t & 1) ? h1fa : h1fb, nullptr, 0,
               tb * BT, th * 32);
}

// One block per batch row. y_{step-1} = h.Wfc + b, then flash-style attention
// over E with one-tile register prefetch (verified rounds 7/10/12).
// step==PL_: y only.
__global__ __launch_bounds__(256) void attn_step_kernel(
    const float* __restrict__ hf, const u16* __restrict__ E,
    const float* __restrict__ Wfc, const float* __restrict__ bfc,
    u16* __restrict__ ctxb, float* __restrict__ yprev,
    float* __restrict__ out, int step)
{
    __shared__ float hs[H_];
    __shared__ float red[256];
    __shared__ u16 Es[48 * H_];
    __shared__ float scores[48];
    const int tid = threadIdx.x;
    const int b = blockIdx.x;

    hs[tid]       = hf[((size_t)b << 9) + tid];
    hs[tid + 256] = hf[((size_t)b << 9) + tid + 256];
    __syncthreads();

    float p = hs[tid] * Wfc[tid] + hs[tid + 256] * Wfc[tid + 256];
    red[tid] = p;
    __syncthreads();
    for (int s = 128; s > 0; s >>= 1) {
        if (tid < s) red[tid] += red[tid + s];
        __syncthreads();
    }
    if (tid == 0) {
        if (step > 0) {
            float y = red[0] + bfc[0];
            yprev[b] = y;
            out[b * PL_ + (step - 1)] = y;
        } else {
            yprev[b] = 0.0f;   // reference: y0 = zeros
        }
    }
    if (step == PL_) return;   // final launch: y only

    const int wv = tid >> 6, lane = tid & 63;
    float m = -1e30f, d = 0.0f, c0a = 0.0f, c1a = 0.0f;
    const int k0 = tid, k1 = tid + 256;
    const uint4* Ebase = (const uint4*)(E + (((size_t)b * L_) << 9));
    uint4 pre[12];
    #pragma unroll
    for (int i = 0; i < 12; ++i) pre[i] = Ebase[tid + (i << 8)];

    for (int l0 = 0; l0 < L_; l0 += 48) {
        __syncthreads();
        {
            uint4* dst = (uint4*)Es;
            #pragma unroll
            for (int i = 0; i < 12; ++i) dst[tid + (i << 8)] = pre[i];
        }
        __syncthreads();
        if (l0 + 48 < L_) {
            const uint4* nx = Ebase + ((size_t)(l0 + 48) << 6);
            #pragma unroll
            for (int i = 0; i < 12; ++i) pre[i] = nx[tid + (i << 8)];
        }
        #pragma unroll
        for (int s = 0; s < 12; ++s) {
            const int l = wv * 12 + s;
            const u16* er = &Es[(l << 9) + (lane << 3)];
            float acc = 0.f;
            #pragma unroll
            for (int j = 0; j < 8; ++j)
                acc += hs[(lane << 3) + j] * b2f(er[j]);
            #pragma unroll
            for (int off = 32; off > 0; off >>= 1)
                acc += __shfl_xor(acc, off);
            if (lane == 0) scores[l] = acc;
        }
        __syncthreads();
        float mc = m;
        #pragma unroll
        for (int l = 0; l < 48; ++l) mc = fmaxf(mc, scores[l]);
        const float alpha = __expf(m - mc);
        d *= alpha; c0a *= alpha; c1a *= alpha;
        for (int l = 0; l < 48; ++l) {
            const float pl = __expf(scores[l] - mc);
            d += pl;
            c0a += pl * b2f(Es[(l << 9) + k0]);
            c1a += pl * b2f(Es[(l << 9) + k1]);
        }
        m = mc;
    }
    const float inv = 1.0f / d;
    ctxb[((size_t)b << 9) + k0] = f2b(c0a * inv);
    ctxb[((size_t)b << 9) + k1] = f2b(c1a * inv);
}

// One-time (per call) weight conversion fp32->bf16, bias fusion, x padding to K=64.
__global__ __launch_bounds__(256) void prep_kernel(
    const float* __restrict__ x,
    const float* __restrict__ Wih0, const float* __restrict__ Whh0,
    const float* __restrict__ bih0, const float* __restrict__ bhh0,
    const float* __restrict__ Wih1, const float* __restrict__ Whh1,
    const float* __restrict__ bih1, const float* __restrict__ bhh1,
    const float* __restrict__ Wdih, const float* __restrict__ Wdhh,
    const float* __restrict__ bihd, const float* __restrict__ bhhd,
    u16* Wih0p, u16* Whh0b, u16* Wih1b, u16* Whh1b, u16* Wdihb, u16* Wdhhb,
    float* w0col, float* bias0, float* bias1, float* biasd, u16* xpad)
{
    const long E0 = 131072;
    const long E1 = E0 + 1048576;
    const long E2 = E1 + 1048576;
    const long E3 = E2 + 1048576;
    const long E4 = E3 + 1048576;
    const long E5 = E4 + 1048576;
    const long E6 = E5 + 2048;
    const long E7 = E6 + 2048;
    const long E8 = E7 + 2048;
    const long E9 = E8 + 2048;
    const long E10 = E9 + (long)B_ * L_ * KC;
    for (long idx = (long)blockIdx.x * 256 + threadIdx.x; idx < E10;
         idx += (long)gridDim.x * 256) {
        if (idx < E0) {
            long r = idx >> 6, cc = idx & 63;
            Wih0p[idx] = f2b(cc < NIN ? Wih0[(r << 3) + cc] : 0.0f);
        } else if (idx < E1) { long j = idx - E0; Whh0b[j] = f2b(Whh0[j]);
        } else if (idx < E2) { long j = idx - E1; Wih1b[j] = f2b(Wih1[j]);
        } else if (idx < E3) { long j = idx - E2; Whh1b[j] = f2b(Whh1[j]);
        } else if (idx < E4) {
            long j = idx - E3; long r = j >> 9, cc = j & 511;
            Wdihb[j] = f2b(Wdih[r * 513 + 1 + cc]);
        } else if (idx < E5) { long j = idx - E4; Wdhhb[j] = f2b(Wdhh[j]);
        } else if (idx < E6) { long j = idx - E5; w0col[j] = Wdih[j * 513];
        } else if (idx < E7) { long j = idx - E6; bias0[j] = bih0[j] + bhh0[j];
        } else if (idx < E8) { long j = idx - E7; bias1[j] = bih1[j] + bhh1[j];
        } else if (idx < E9) { long j = idx - E8; biasd[j] = bihd[j] + bhhd[j];
        } else {
            long j = idx - E9;
            long b = j / (L_ * KC);
            long rest = j - b * (L_ * KC);
            long l = rest >> 6, n = rest & 63;
            xpad[j] = f2b(n < NIN ? x[(b * L_ + l) * NIN + n] : 0.0f);
        }
    }
}

extern "C" void kernel_launch(void* const* d_in, const int* in_sizes, int n_in,
                              void* d_out, int out_size, void* d_ws, size_t ws_size,
                              hipStream_t stream)
{
    (void)in_sizes; (void)n_in; (void)out_size; (void)ws_size;
    const float* x    = (const float*)d_in[0];
    const float* Wih0 = (const float*)d_in[1];
    const float* Whh0 = (const float*)d_in[2];
    const float* bih0 = (const float*)d_in[3];
    const float* bhh0 = (const float*)d_in[4];
    const float* Wih1 = (const float*)d_in[5];
    const float* Whh1 = (const float*)d_in[6];
    const float* bih1 = (const float*)d_in[7];
    const float* bhh1 = (const float*)d_in[8];
    const float* Wdih = (const float*)d_in[9];
    const float* Wdhh = (const float*)d_in[10];
    const float* bihd = (const float*)d_in[11];
    const float* bhhd = (const float*)d_in[12];
    const float* Wfc  = (const float*)d_in[13];
    const float* bfc  = (const float*)d_in[14];
    float* out = (float*)d_out;

    char* ws = (char*)d_ws;
    float* c0    = (float*)(ws + 0);
    float* c1    = (float*)(ws + 524288);
    u16*   h0a   = (u16*)(ws + 1048576);
    u16*   h1a   = (u16*)(ws + 1310720);
    // zero region ends at 1572864
    u16*   h0b   = (u16*)(ws + 1572864);
    u16*   h1b   = (u16*)(ws + 1835008);
    float* h1fa  = (float*)(ws + 2097152);
    float* h1fb  = (float*)(ws + 2621440);
    u16*   ctxb  = (u16*)(ws + 3145728);
    float* ypv   = (float*)(ws + 3407872);
    u16*   Wih0p = (u16*)(ws + 3408896);
    u16*   Whh0b = (u16*)(ws + 3671040);
    u16*   Wih1b = (u16*)(ws + 5768192);
    u16*   Whh1b = (u16*)(ws + 7865344);
    u16*   Wdihb = (u16*)(ws + 9962496);
    u16*   Wdhhb = (u16*)(ws + 12059648);
    float* w0col = (float*)(ws + 14156800);
    float* bias0 = (float*)(ws + 14164992);
    float* bias1 = (float*)(ws + 14173184);
    float* biasd = (float*)(ws + 14181376);
    u16*   xpad  = (u16*)(ws + 14189568);
    u16*   E     = (u16*)(ws + 25199616);
    // total workspace use: 113,280,000 bytes

    hipMemsetAsync(d_ws, 0, 1572864, stream);  // c0, c1, h0[0], h1[0] = 0

    prep_kernel<<<512, 256, 0, stream>>>(x, Wih0, Whh0, bih0, bhh0,
        Wih1, Whh1, bih1, bhh1, Wdih, Wdhh, bihd, bhhd,
        Wih0p, Whh0b, Wih1b, Whh1b, Wdihb, Wdhhb, w0col, bias0, bias1, biasd, xpad);

    for (int tau = 0; tau <= L_; ++tau)
        enc_step_kernel<<<256, 256, 0, stream>>>(xpad, Wih0p, Whh0b, bias0,
            Wih1b, Whh1b, bias1, h0a, h0b, c0, h1a, h1b, h1fa, h1fb, c1, E, tau);

    for (int t = 0; t < PL_; ++t) {
        attn_step_kernel<<<256, 256, 0, stream>>>((t & 1) ? h1fb : h1fa, E,
            Wfc, bfc, ctxb, ypv, out, t);
        dec_step_kernel<<<128, 256, 0, stream>>>(ctxb, ypv, Wdihb, Wdhhb,
            biasd, w0col, h1a, h1b, h1fa, h1fb, c1, t);
    }
    attn_step_kernel<<<256, 256, 0, stream>>>(h1fa, E, Wfc, bfc, ctxb, ypv, out, PL_);
}

// Round 15
// 13579.475 us; speedup vs baseline: 3.6794x; 1.5757x over previous
//
#include <hip/hip_runtime.h>
#include <hip/hip_bf16.h>

#define B_   256
#define L_   336
#define NIN  8
#define H_   512
#define PL_  96
#define KC   64
#define BT   32
#define GT   64

typedef unsigned short u16;
typedef __attribute__((ext_vector_type(8))) short short8;
typedef __attribute__((ext_vector_type(4))) float f32x4;

__device__ __forceinline__ float sigm(float x)   { return 1.0f / (1.0f + __expf(-x)); }
__device__ __forceinline__ float tanhf_(float x) { return 1.0f - 2.0f / (1.0f + __expf(2.0f * x)); }
__device__ __forceinline__ u16 f2b(float f) {
    __hip_bfloat16 h = __float2bfloat16(f);
    return __builtin_bit_cast(u16, h);
}
__device__ __forceinline__ float b2f(u16 u) {
    union { unsigned int i; float f; } v; v.i = ((unsigned int)u) << 16; return v.f;
}

struct Seg { const u16* src; int stride; const u16* W; int nch; int ldw; };

// Gate-split tile: [32 batch x 64 gates] per block (j-tile of 16 per gate
// type q). LDS 22.2 KB -> 2 blocks/CU co-resident (every profile this
// session showed 12% occupancy = 1 wave/SIMD = zero latency hiding; m114:
// co-resident blocks' MFMA and staging overlap). W reads are PARTITIONED
// by the gate split (redundancy unchanged vs baseline); only the small
// A-panel is read 2x more. All math = verified baseline with j-tile=16.
struct SMG {
    u16   in_s[BT][KC + 8];     // 4.6 KB
    u16   w_s[GT][KC + 8];      // 9.2 KB
    float g_s[GT][BT + 1];      // 8.4 KB  -> 22.2 KB
};

// One block: batch tile BT=32 x 64 gate rows (q*512 + j0 + u, u in [0,16)).
// 4 waves; wave wv = gate type q: 2 m-tiles x 1 n-tile of 16x16x32 MFMA.
__device__ void gates_gemm_cell(const Seg* segs,
    const float* __restrict__ bias, const float* __restrict__ w0col,
    const float* __restrict__ yprev,
    float* __restrict__ cbuf, u16* __restrict__ hbf_out, float* __restrict__ hf_out,
    u16* __restrict__ Ebuf, int te, int batch0, int j0, SMG& sm)
{
    const int tid = threadIdx.x;
    const int wv = tid >> 6, lane = tid & 63;
    f32x4 acc[2] = {};

    for (int s = 0; s < 2; ++s) {
        const Seg sg = segs[s];
        for (int c = 0; c < sg.nch; ++c) {
            const int k0 = c * KC;
            __syncthreads();
            {   // stage A: 32 rows x 64 bf16 = 256 uint4, 1/thread (verbatim baseline)
                const int b = tid >> 3, kq = tid & 7;
                const uint4* p = (const uint4*)(sg.src + (size_t)(batch0 + b) * sg.stride + k0) + kq;
                *(uint4*)&sm.in_s[b][kq << 3] = *p;
            }
            #pragma unroll
            for (int i = 0; i < 2; ++i) {  // stage W: 64 rows x 64 bf16 = 512 uint4, 2/thread
                const int idx = tid + (i << 8);
                const int gi = idx >> 3, kq = idx & 7;
                const int row = ((gi >> 4) << 9) + j0 + (gi & 15);   // q*512 + j0 + u
                const uint4* p = (const uint4*)(sg.W + (size_t)row * sg.ldw + k0) + kq;
                *(uint4*)&sm.w_s[gi][kq << 3] = *p;
            }
            __syncthreads();
            #pragma unroll
            for (int ks = 0; ks < 2; ++ks) {
                const int kk = (ks << 5) + ((lane >> 4) << 3);
                short8 a0 = *(const short8*)&sm.in_s[lane & 15][kk];
                short8 a1 = *(const short8*)&sm.in_s[16 + (lane & 15)][kk];
                const int gi = (wv << 4) + (lane & 15);
                short8 bb = *(const short8*)&sm.w_s[gi][kk];
                acc[0] = __builtin_amdgcn_mfma_f32_16x16x32_bf16(a0, bb, acc[0], 0, 0, 0);
                acc[1] = __builtin_amdgcn_mfma_f32_16x16x32_bf16(a1, bb, acc[1], 0, 0, 0);
            }
        }
    }
    __syncthreads();
    // C/D layout (m89-verified): col(n)=lane&15, row(m)=(lane>>4)*4+reg
    #pragma unroll
    for (int mt = 0; mt < 2; ++mt) {
        const int gi = (wv << 4) + (lane & 15);
        const int brow = (mt << 4) + ((lane >> 4) << 2);
        #pragma unroll
        for (int r = 0; r < 4; ++r)
            sm.g_s[gi][brow + r] = acc[mt][r];
    }
    __syncthreads();

    // LSTM cell: 32b x 16j = 512 outputs, 2/thread
    #pragma unroll
    for (int e = 0; e < 2; ++e) {
        const int idx = tid + (e << 8);
        const int b = idx >> 4, j = idx & 15;
        const int bg = batch0 + b, jg = j0 + j;
        float pre[4];
        #pragma unroll
        for (int q = 0; q < 4; ++q) {
            const int r = (q << 9) + jg;
            float v = sm.g_s[(q << 4) + j][b] + bias[r];
            if (w0col) v += yprev[bg] * w0col[r];
            pre[q] = v;
        }
        const float iv = sigm(pre[0]);
        const float fv = sigm(pre[1]);
        const float gv = tanhf_(pre[2]);
        const float ov = sigm(pre[3]);
        const size_t ci = ((size_t)bg << 9) + jg;
        const float cold = cbuf[ci];
        const float cn = fv * cold + iv * gv;
        const float hn = ov * tanhf_(cn);
        cbuf[ci] = cn;
        hbf_out[ci] = f2b(hn);
        if (hf_out) hf_out[ci] = hn;
        if (Ebuf) Ebuf[((size_t)bg * L_ + te) * H_ + jg] = f2b(hn);
    }
}

// Pipelined encoder: blocks 0..255 do L0 step tau; 256..511 do L1 step tau-1.
// 512 blocks on 256 CUs -> 2 blocks/CU (the occupancy lever).
__global__ __launch_bounds__(256) void enc_step_kernel(
    const u16* __restrict__ xpad, const u16* __restrict__ Wih0p, const u16* __restrict__ Whh0b,
    const float* __restrict__ bias0,
    const u16* __restrict__ Wih1b, const u16* __restrict__ Whh1b, const float* __restrict__ bias1,
    u16* h0a, u16* h0b, float* c0,
    u16* h1a, u16* h1b, float* h1fa, float* h1fb, float* c1,
    u16* E, int tau)
{
    __shared__ SMG sm;
    const int bid = blockIdx.x;
    if (bid < 256) {
        if (tau >= L_) return;
        const int tb = bid & 7, th = bid >> 3;      // th in [0,32)
        Seg segs[2];
        segs[0] = { xpad + tau * KC, L_ * KC, Wih0p, 1, KC };
        segs[1] = { (tau & 1) ? h0b : h0a, H_, Whh0b, 8, H_ };
        gates_gemm_cell(segs, bias0, nullptr, nullptr, c0,
                        (tau & 1) ? h0a : h0b, nullptr, nullptr, 0,
                        tb * BT, th * 16, sm);
    } else {
        if (tau == 0) return;
        const int te = tau - 1;
        const int id = bid - 256;
        const int tb = id & 7, th = id >> 3;
        Seg segs[2];
        segs[0] = { (tau & 1) ? h0b : h0a, H_, Wih1b, 8, H_ };  // ys0[te]
        segs[1] = { (te & 1) ? h1b : h1a, H_, Whh1b, 8, H_ };
        gates_gemm_cell(segs, bias1, nullptr, nullptr, c1,
                        (te & 1) ? h1a : h1b, (te & 1) ? h1fa : h1fb, E, te,
                        tb * BT, th * 16, sm);
    }
}

__global__ __launch_bounds__(256) void dec_step_kernel(
    const u16* __restrict__ ctxb, const float* __restrict__ yprev,
    const u16* __restrict__ Wdihb, const u16* __restrict__ Wdhhb,
    const float* __restrict__ biasd, const float* __restrict__ w0col,
    u16* h1a, u16* h1b, float* h1fa, float* h1fb, float* c1, int t)
{
    __shared__ SMG sm;
    const int bid = blockIdx.x;
    const int tb = bid & 7, th = bid >> 3;          // 256 blocks: th in [0,32)
    Seg segs[2];
    segs[0] = { ctxb, H_, Wdihb, 8, H_ };
    segs[1] = { (t & 1) ? h1b : h1a, H_, Wdhhb, 8, H_ };
    gates_gemm_cell(segs, biasd, w0col, yprev, c1,
                    (t & 1) ? h1a : h1b, (t & 1) ? h1fa : h1fb, nullptr, 0,
                    tb * BT, th * 16, sm);
}

// One block per batch row. y_{step-1} = h.Wfc + b, then flash-style attention
// over E with one-tile register prefetch (verified rounds 7/12/14).
// step==PL_: y only.
__global__ __launch_bounds__(256) void attn_step_kernel(
    const float* __restrict__ hf, const u16* __restrict__ E,
    const float* __restrict__ Wfc, const float* __restrict__ bfc,
    u16* __restrict__ ctxb, float* __restrict__ yprev,
    float* __restrict__ out, int step)
{
    __shared__ float hs[H_];
    __shared__ float red[256];
    __shared__ u16 Es[48 * H_];
    __shared__ float scores[48];
    const int tid = threadIdx.x;
    const int b = blockIdx.x;

    hs[tid]       = hf[((size_t)b << 9) + tid];
    hs[tid + 256] = hf[((size_t)b << 9) + tid + 256];
    __syncthreads();

    float p = hs[tid] * Wfc[tid] + hs[tid + 256] * Wfc[tid + 256];
    red[tid] = p;
    __syncthreads();
    for (int s = 128; s > 0; s >>= 1) {
        if (tid < s) red[tid] += red[tid + s];
        __syncthreads();
    }
    if (tid == 0) {
        if (step > 0) {
            float y = red[0] + bfc[0];
            yprev[b] = y;
            out[b * PL_ + (step - 1)] = y;
        } else {
            yprev[b] = 0.0f;   // reference: y0 = zeros
        }
    }
    if (step == PL_) return;   // final launch: y only

    const int wv = tid >> 6, lane = tid & 63;
    float m = -1e30f, d = 0.0f, c0a = 0.0f, c1a = 0.0f;
    const int k0 = tid, k1 = tid + 256;
    const uint4* Ebase = (const uint4*)(E + (((size_t)b * L_) << 9));
    uint4 pre[12];
    #pragma unroll
    for (int i = 0; i < 12; ++i) pre[i] = Ebase[tid + (i << 8)];

    for (int l0 = 0; l0 < L_; l0 += 48) {
        __syncthreads();
        {
            uint4* dst = (uint4*)Es;
            #pragma unroll
            for (int i = 0; i < 12; ++i) dst[tid + (i << 8)] = pre[i];
        }
        __syncthreads();
        if (l0 + 48 < L_) {
            const uint4* nx = Ebase + ((size_t)(l0 + 48) << 6);
            #pragma unroll
            for (int i = 0; i < 12; ++i) pre[i] = nx[tid + (i << 8)];
        }
        #pragma unroll
        for (int s = 0; s < 12; ++s) {
            const int l = wv * 12 + s;
            const u16* er = &Es[(l << 9) + (lane << 3)];
            float acc = 0.f;
            #pragma unroll
            for (int j = 0; j < 8; ++j)
                acc += hs[(lane << 3) + j] * b2f(er[j]);
            #pragma unroll
            for (int off = 32; off > 0; off >>= 1)
                acc += __shfl_xor(acc, off);
            if (lane == 0) scores[l] = acc;
        }
        __syncthreads();
        float mc = m;
        #pragma unroll
        for (int l = 0; l < 48; ++l) mc = fmaxf(mc, scores[l]);
        const float alpha = __expf(m - mc);
        d *= alpha; c0a *= alpha; c1a *= alpha;
        for (int l = 0; l < 48; ++l) {
            const float pl = __expf(scores[l] - mc);
            d += pl;
            c0a += pl * b2f(Es[(l << 9) + k0]);
            c1a += pl * b2f(Es[(l << 9) + k1]);
        }
        m = mc;
    }
    const float inv = 1.0f / d;
    ctxb[((size_t)b << 9) + k0] = f2b(c0a * inv);
    ctxb[((size_t)b << 9) + k1] = f2b(c1a * inv);
}

// One-time (per call) weight conversion fp32->bf16, bias fusion, x padding to K=64.
__global__ __launch_bounds__(256) void prep_kernel(
    const float* __restrict__ x,
    const float* __restrict__ Wih0, const float* __restrict__ Whh0,
    const float* __restrict__ bih0, const float* __restrict__ bhh0,
    const float* __restrict__ Wih1, const float* __restrict__ Whh1,
    const float* __restrict__ bih1, const float* __restrict__ bhh1,
    const float* __restrict__ Wdih, const float* __restrict__ Wdhh,
    const float* __restrict__ bihd, const float* __restrict__ bhhd,
    u16* Wih0p, u16* Whh0b, u16* Wih1b, u16* Whh1b, u16* Wdihb, u16* Wdhhb,
    float* w0col, float* bias0, float* bias1, float* biasd, u16* xpad)
{
    const long E0 = 131072;
    const long E1 = E0 + 1048576;
    const long E2 = E1 + 1048576;
    const long E3 = E2 + 1048576;
    const long E4 = E3 + 1048576;
    const long E5 = E4 + 1048576;
    const long E6 = E5 + 2048;
    const long E7 = E6 + 2048;
    const long E8 = E7 + 2048;
    const long E9 = E8 + 2048;
    const long E10 = E9 + (long)B_ * L_ * KC;
    for (long idx = (long)blockIdx.x * 256 + threadIdx.x; idx < E10;
         idx += (long)gridDim.x * 256) {
        if (idx < E0) {
            long r = idx >> 6, cc = idx & 63;
            Wih0p[idx] = f2b(cc < NIN ? Wih0[(r << 3) + cc] : 0.0f);
        } else if (idx < E1) { long j = idx - E0; Whh0b[j] = f2b(Whh0[j]);
        } else if (idx < E2) { long j = idx - E1; Wih1b[j] = f2b(Wih1[j]);
        } else if (idx < E3) { long j = idx - E2; Whh1b[j] = f2b(Whh1[j]);
        } else if (idx < E4) {
            long j = idx - E3; long r = j >> 9, cc = j & 511;
            Wdihb[j] = f2b(Wdih[r * 513 + 1 + cc]);
        } else if (idx < E5) { long j = idx - E4; Wdhhb[j] = f2b(Wdhh[j]);
        } else if (idx < E6) { long j = idx - E5; w0col[j] = Wdih[j * 513];
        } else if (idx < E7) { long j = idx - E6; bias0[j] = bih0[j] + bhh0[j];
        } else if (idx < E8) { long j = idx - E7; bias1[j] = bih1[j] + bhh1[j];
        } else if (idx < E9) { long j = idx - E8; biasd[j] = bihd[j] + bhhd[j];
        } else {
            long j = idx - E9;
            long b = j / (L_ * KC);
            long rest = j - b * (L_ * KC);
            long l = rest >> 6, n = rest & 63;
            xpad[j] = f2b(n < NIN ? x[(b * L_ + l) * NIN + n] : 0.0f);
        }
    }
}

extern "C" void kernel_launch(void* const* d_in, const int* in_sizes, int n_in,
                              void* d_out, int out_size, void* d_ws, size_t ws_size,
                              hipStream_t stream)
{
    (void)in_sizes; (void)n_in; (void)out_size; (void)ws_size;
    const float* x    = (const float*)d_in[0];
    const float* Wih0 = (const float*)d_in[1];
    const float* Whh0 = (const float*)d_in[2];
    const float* bih0 = (const float*)d_in[3];
    const float* bhh0 = (const float*)d_in[4];
    const float* Wih1 = (const float*)d_in[5];
    const float* Whh1 = (const float*)d_in[6];
    const float* bih1 = (const float*)d_in[7];
    const float* bhh1 = (const float*)d_in[8];
    const float* Wdih = (const float*)d_in[9];
    const float* Wdhh = (const float*)d_in[10];
    const float* bihd = (const float*)d_in[11];
    const float* bhhd = (const float*)d_in[12];
    const float* Wfc  = (const float*)d_in[13];
    const float* bfc  = (const float*)d_in[14];
    float* out = (float*)d_out;

    char* ws = (char*)d_ws;
    float* c0    = (float*)(ws + 0);
    float* c1    = (float*)(ws + 524288);
    u16*   h0a   = (u16*)(ws + 1048576);
    u16*   h1a   = (u16*)(ws + 1310720);
    // zero region ends at 1572864
    u16*   h0b   = (u16*)(ws + 1572864);
    u16*   h1b   = (u16*)(ws + 1835008);
    float* h1fa  = (float*)(ws + 2097152);
    float* h1fb  = (float*)(ws + 2621440);
    u16*   ctxb  = (u16*)(ws + 3145728);
    float* ypv   = (float*)(ws + 3407872);
    u16*   Wih0p = (u16*)(ws + 3408896);
    u16*   Whh0b = (u16*)(ws + 3671040);
    u16*   Wih1b = (u16*)(ws + 5768192);
    u16*   Whh1b = (u16*)(ws + 7865344);
    u16*   Wdihb = (u16*)(ws + 9962496);
    u16*   Wdhhb = (u16*)(ws + 12059648);
    float* w0col = (float*)(ws + 14156800);
    float* bias0 = (float*)(ws + 14164992);
    float* bias1 = (float*)(ws + 14173184);
    float* biasd = (float*)(ws + 14181376);
    u16*   xpad  = (u16*)(ws + 14189568);
    u16*   E     = (u16*)(ws + 25199616);
    // total workspace use: 113,280,000 bytes

    hipMemsetAsync(d_ws, 0, 1572864, stream);  // c0, c1, h0[0], h1[0] = 0

    prep_kernel<<<512, 256, 0, stream>>>(x, Wih0, Whh0, bih0, bhh0,
        Wih1, Whh1, bih1, bhh1, Wdih, Wdhh, bihd, bhhd,
        Wih0p, Whh0b, Wih1b, Whh1b, Wdihb, Wdhhb, w0col, bias0, bias1, biasd, xpad);

    for (int tau = 0; tau <= L_; ++tau)
        enc_step_kernel<<<512, 256, 0, stream>>>(xpad, Wih0p, Whh0b, bias0,
            Wih1b, Whh1b, bias1, h0a, h0b, c0, h1a, h1b, h1fa, h1fb, c1, E, tau);

    for (int t = 0; t < PL_; ++t) {
        attn_step_kernel<<<256, 256, 0, stream>>>((t & 1) ? h1fb : h1fa, E,
            Wfc, bfc, ctxb, ypv, out, t);
        dec_step_kernel<<<256, 256, 0, stream>>>(ctxb, ypv, Wdihb, Wdhhb,
            biasd, w0col, h1a, h1b, h1fa, h1fb, c1, t);
    }
    attn_step_kernel<<<256, 256, 0, stream>>>(h1fa, E, Wfc, bfc, ctxb, ypv, out, PL_);
}